// Round 15
// baseline (406.432 us; speedup 1.0000x reference)
//
#include <hip/hip_runtime.h>

typedef _Float16 f16;
typedef _Float16 f16x2 __attribute__((ext_vector_type(2)));
typedef _Float16 f16x8 __attribute__((ext_vector_type(8)));
typedef float f32x16 __attribute__((ext_vector_type(16)));
typedef unsigned int u32;
typedef unsigned short u16;

#define MFMA(a, b, c) __builtin_amdgcn_mfma_f32_32x32x16_f16((a), (b), (c), 0, 0, 0)

// K/V LDS row strides padded to non-multiples of 128B so bank index depends on
// the row (2*row term), not just the 8 chunk slots -> <=2-way aliasing (free)
// while keeping single ds_read_b128 per fragment.
#define KSTRIDE 136
#define VSTRIDE 520

// RNE f16 pack
__device__ __forceinline__ u32 pk2(float a, float b) {
  union { f16x2 h; u32 u; } x;
  x.h[0] = (f16)a; x.h[1] = (f16)b;
  return x.u;
}
__device__ __forceinline__ float2 up2(u32 u) {
  union { u32 u_; f16x2 h; } x; x.u_ = u;
  return make_float2((float)x.h[0], (float)x.h[1]);
}
__device__ __forceinline__ f16x8 mk8(u32 a, u32 b, u32 c, u32 d) {
  union { u32 u[4]; f16x8 v; } x;
  x.u[0] = a; x.u[1] = b; x.u[2] = c; x.u[3] = d;
  return x.v;
}
__device__ __forceinline__ u16 f16b(float v) {
  union { f16 h; u16 u; } x; x.h = (f16)v; return x.u;
}
__device__ __forceinline__ float ex2(float x) {
#if __has_builtin(__builtin_amdgcn_exp2f)
  return __builtin_amdgcn_exp2f(x);
#else
  return exp2f(x);
#endif
}

// RNE pack pair + scaled residual (hi unbiased half-ulp; lo absorbs it exactly).
__device__ __forceinline__ void sp2(float a, float b, float S, u32* hi, u32* lo) {
  union { f16x2 h; u32 u; } xh, xl;
  xh.h[0] = (f16)a; xh.h[1] = (f16)b;
  float ra = (a - (float)xh.h[0]) * S;
  float rb = (b - (float)xh.h[1]) * S;
  xl.h[0] = (f16)ra; xl.h[1] = (f16)rb;
  *hi = xh.u; *lo = xl.u;
}

template<int CTRL>
__device__ __forceinline__ float dpp_add(float v) {
  int t = __builtin_amdgcn_update_dpp(0, __builtin_bit_cast(int, v), CTRL, 0xF, 0xF, true);
  return v + __builtin_bit_cast(float, t);
}
// sum over each 32-lane half
__device__ __forceinline__ float red32(float v) {
  v = dpp_add<0xB1>(v);   // xor 1
  v = dpp_add<0x4E>(v);   // xor 2
  v = dpp_add<0x141>(v);  // xor 7 (row_half_mirror)
  v = dpp_add<0x140>(v);  // xor 15 (row_mirror)
  int sw = __builtin_amdgcn_ds_swizzle(__builtin_bit_cast(int, v), 0x401F); // xor 16
  return v + __builtin_bit_cast(float, sw);
}

// D-layout f32x16 -> single A/B fragment (k = 16*kt1 + 8*g5 + e), RNE.
__device__ __forceinline__ f16x8 xfrag(const f32x16 a, int kt1, int g5) {
  u32 u0, u1, u2, u3;
  if (kt1 == 0) {
    u0 = pk2(a[0], a[1]);   u1 = pk2(a[2], a[3]);
    u2 = pk2(a[4], a[5]);   u3 = pk2(a[6], a[7]);
  } else {
    u0 = pk2(a[8], a[9]);   u1 = pk2(a[10], a[11]);
    u2 = pk2(a[12], a[13]); u3 = pk2(a[14], a[15]);
  }
  u32 s0 = (u32)__shfl_xor((int)u0, 32);
  u32 s1 = (u32)__shfl_xor((int)u1, 32);
  u32 s2 = (u32)__shfl_xor((int)u2, 32);
  u32 s3 = (u32)__shfl_xor((int)u3, 32);
  u32 r0 = g5 ? s2 : u0;
  u32 r1 = g5 ? s3 : u1;
  u32 r2 = g5 ? u2 : s0;
  u32 r3 = g5 ? u3 : s1;
  return mk8(r0, r1, r2, r3);
}

// split hi/lo (lo scaled by S) variant
__device__ __forceinline__ void xfrag2(const f32x16 a, int kt1, int g5,
                                       f16x8* hi, f16x8* lo, float S) {
  u32 uh[4], ul[4];
#pragma unroll
  for (int j = 0; j < 4; ++j) {
    float v0 = kt1 ? a[8 + 2 * j] : a[2 * j];
    float v1 = kt1 ? a[9 + 2 * j] : a[2 * j + 1];
    sp2(v0, v1, S, &uh[j], &ul[j]);
  }
  u32 sh[4], sl[4];
#pragma unroll
  for (int j = 0; j < 4; ++j) {
    sh[j] = (u32)__shfl_xor((int)uh[j], 32);
    sl[j] = (u32)__shfl_xor((int)ul[j], 32);
  }
  *hi = mk8(g5 ? sh[2] : uh[0], g5 ? sh[3] : uh[1],
            g5 ? uh[2] : sh[0], g5 ? uh[3] : sh[1]);
  *lo = mk8(g5 ? sl[2] : ul[0], g5 ? sl[3] : ul[1],
            g5 ? ul[2] : sl[0], g5 ? ul[3] : sl[1]);
}

// W-plane read: 8B-granule, XOR-(row&15) — R11-proven layout.
__device__ __forceinline__ f16x8 ldfrag(const char* plane, int row, int kt, int g5) {
  int s = row & 15;
  int c8 = 4 * kt + 2 * g5;
  uint2 a = *(const uint2*)(plane + row * 128 + ((c8) ^ s) * 8);
  uint2 b = *(const uint2*)(plane + row * 128 + ((c8 + 1) ^ s) * 8);
  return mk8(a.x, a.y, b.x, b.y);
}

// ---------------- K1: [N,C,F,T] f32 -> x[B=n*256+t][F][C] f32 (into d_out) ----
__global__ __launch_bounds__(256) void k_pre32(const float* __restrict__ inp,
                                               float* __restrict__ xws) {
  __shared__ float tile[64 * 65];
  const int bid = blockIdx.x;
  const int n = bid >> 10;
  const int rem = bid & 1023;
  const int f = rem >> 2;
  const int t0 = (rem & 3) << 6;
  const int tid = threadIdx.x;

  const int tt = tid & 63, cb = tid >> 6;
  const float* src = inp + ((size_t)n * 64 * 256 + f) * 256 + t0;
#pragma unroll
  for (int k = 0; k < 16; ++k) {
    int c = cb * 16 + k;
    tile[c * 65 + tt] = src[(size_t)c * 65536 + tt];
  }
  __syncthreads();
  const int c2 = (tid & 31) * 2, tb = tid >> 5;
#pragma unroll
  for (int k = 0; k < 8; ++k) {
    int t = tb + 8 * k;
    float2 v = make_float2(tile[c2 * 65 + t], tile[(c2 + 1) * 65 + t]);
    *(float2*)(xws + ((size_t)(n * 256 + t0 + t) * 256 + f) * 64 + c2) = v;
  }
}

// ---------------- K2: fused LN1+QKV+attn+LN2+proj+LN3+PReLU ----------------
// 512 threads = 8 waves; wave w owns F-rows [32w, 32w+32).
// K/V: 16B-chunk xor-7 + padded row strides (conflict-free b128).
// W planes: 8B-granule xor-15 (R11-proven). PV uses single-f16 P (post-softmax
// errors are relative and LN2-invariant; the split mattered only pre-softmax).
__global__ __launch_bounds__(512, 2) void k_attn(
    const float* __restrict__ xg,  // x f32 [b][f][c] (staged in d_out)
    u16* __restrict__ yws,         // y f16 out
    const float* __restrict__ Wq, const float* __restrict__ bq,
    const float* __restrict__ Wk, const float* __restrict__ bk,
    const float* __restrict__ Wv, const float* __restrict__ bv,
    const float* __restrict__ g1, const float* __restrict__ b1,
    const float* __restrict__ g2, const float* __restrict__ b2,
    const float* __restrict__ Wt, const float* __restrict__ bt,
    const float* __restrict__ g3, const float* __restrict__ b3,
    const float* __restrict__ alp) {
  extern __shared__ char smem[];
  char* Khi = smem;                   // K hi f16 [256][136B] padded
  char* Klo = smem + 34816;           // K residual*512, same stride
  char* Vlds = smem + 69632;          // Vt f16 [64][520B] padded
  char* WkH = smem + 102912;          // W planes: [64 rows][16 granules], xor-15
  char* WkL = smem + 111104;
  char* WvH = smem + 119296;
  char* WvL = smem + 127488;
  char* WqH = smem + 135680;
  char* WqL = smem + 143872;
  char* WtH = smem + 152064;          // -> total 160256 B

  const int tid = threadIdx.x;
  const int w = tid >> 6;          // 0..7
  const int lane = tid & 63;
  const int l31 = lane & 31;
  const int g5 = lane >> 5;
  const int l7 = l31 & 7;
  const int b = blockIdx.x;
  const float* xb = xg + (size_t)b * 16384;
  const float RLO = 1.f / 512.f;

  // ---- issue x loads early (latency hides under W-prep) ----
  float xv[32];
  {
    int f = 32 * w + l31;
#pragma unroll
    for (int kt = 0; kt < 4; ++kt) {
      float4 a = *(const float4*)(xb + f * 64 + 16 * kt + 8 * g5);
      float4 c = *(const float4*)(xb + f * 64 + 16 * kt + 8 * g5 + 4);
      xv[kt * 8 + 0] = a.x; xv[kt * 8 + 1] = a.y;
      xv[kt * 8 + 2] = a.z; xv[kt * 8 + 3] = a.w;
      xv[kt * 8 + 4] = c.x; xv[kt * 8 + 5] = c.y;
      xv[kt * 8 + 6] = c.z; xv[kt * 8 + 7] = c.w;
    }
  }

  // ---- Phase 0: cooperative W -> LDS split-pack (R11 8B-granule scheme) ----
  {
    const int prow = tid >> 3, pc = tid & 7;
    const int ps = prow & 15;
    const int pha = (2 * pc) ^ ps, phb = (2 * pc + 1) ^ ps;
    const size_t off = (size_t)prow * 64 + pc * 8;
    {
      float4 a = *(const float4*)(Wk + off);
      float4 c = *(const float4*)(Wk + off + 4);
      u32 h0, l0, h1, l1, h2, l2, h3, l3;
      sp2(a.x, a.y, 512.f, &h0, &l0); sp2(a.z, a.w, 512.f, &h1, &l1);
      sp2(c.x, c.y, 512.f, &h2, &l2); sp2(c.z, c.w, 512.f, &h3, &l3);
      *(uint2*)(WkH + prow * 128 + pha * 8) = make_uint2(h0, h1);
      *(uint2*)(WkH + prow * 128 + phb * 8) = make_uint2(h2, h3);
      *(uint2*)(WkL + prow * 128 + pha * 8) = make_uint2(l0, l1);
      *(uint2*)(WkL + prow * 128 + phb * 8) = make_uint2(l2, l3);
    }
    {
      float4 a = *(const float4*)(Wv + off);
      float4 c = *(const float4*)(Wv + off + 4);
      u32 h0, l0, h1, l1, h2, l2, h3, l3;
      sp2(a.x, a.y, 512.f, &h0, &l0); sp2(a.z, a.w, 512.f, &h1, &l1);
      sp2(c.x, c.y, 512.f, &h2, &l2); sp2(c.z, c.w, 512.f, &h3, &l3);
      *(uint2*)(WvH + prow * 128 + pha * 8) = make_uint2(h0, h1);
      *(uint2*)(WvH + prow * 128 + phb * 8) = make_uint2(h2, h3);
      *(uint2*)(WvL + prow * 128 + pha * 8) = make_uint2(l0, l1);
      *(uint2*)(WvL + prow * 128 + phb * 8) = make_uint2(l2, l3);
    }
    {
      float4 a = *(const float4*)(Wq + off);
      float4 c = *(const float4*)(Wq + off + 4);
      u32 h0, l0, h1, l1, h2, l2, h3, l3;
      sp2(a.x, a.y, 512.f, &h0, &l0); sp2(a.z, a.w, 512.f, &h1, &l1);
      sp2(c.x, c.y, 512.f, &h2, &l2); sp2(c.z, c.w, 512.f, &h3, &l3);
      *(uint2*)(WqH + prow * 128 + pha * 8) = make_uint2(h0, h1);
      *(uint2*)(WqH + prow * 128 + phb * 8) = make_uint2(h2, h3);
      *(uint2*)(WqL + prow * 128 + pha * 8) = make_uint2(l0, l1);
      *(uint2*)(WqL + prow * 128 + phb * 8) = make_uint2(l2, l3);
    }
    {
      float4 a = *(const float4*)(Wt + off);
      float4 c = *(const float4*)(Wt + off + 4);
      *(uint2*)(WtH + prow * 128 + pha * 8) = make_uint2(pk2(a.x, a.y), pk2(a.z, a.w));
      *(uint2*)(WtH + prow * 128 + phb * 8) = make_uint2(pk2(c.x, c.y), pk2(c.z, c.w));
    }
  }
  __syncthreads();

  // ---- LN1 (f32) -> split h fragments ----
  f16x8 hhi[4], hlo[4];
  {
    float s = 0.f, sq = 0.f;
#pragma unroll
    for (int i = 0; i < 32; ++i) { s += xv[i]; sq += xv[i] * xv[i]; }
    s += __shfl_xor(s, 32);
    sq += __shfl_xor(sq, 32);
    float mean = s * (1.f / 64.f);
    float var = sq * (1.f / 64.f) - mean * mean;
    float rs = rsqrtf(var + 1e-5f);
#pragma unroll
    for (int kt = 0; kt < 4; ++kt) {
      int c0 = 16 * kt + 8 * g5;
      u32 ph[4], pl[4];
#pragma unroll
      for (int j = 0; j < 4; ++j) {
        float v0 = (xv[kt * 8 + 2 * j] - mean) * rs * g1[c0 + 2 * j] + b1[c0 + 2 * j];
        float v1 = (xv[kt * 8 + 2 * j + 1] - mean) * rs * g1[c0 + 2 * j + 1] + b1[c0 + 2 * j + 1];
        sp2(v0, v1, 512.f, &ph[j], &pl[j]);
      }
      hhi[kt] = mk8(ph[0], ph[1], ph[2], ph[3]);
      hlo[kt] = mk8(pl[0], pl[1], pl[2], pl[3]);
    }
  }

  // ---- K = (Wk split)(h split) + bk -> split store Khi/Klo (16B chunks) ----
  {
    f32x16 ah[2] = {}, al[2] = {};
#pragma unroll
    for (int kt = 0; kt < 4; ++kt) {
#pragma unroll
      for (int ot = 0; ot < 2; ++ot) {
        f16x8 mh = ldfrag(WkH, l31 + 32 * ot, kt, g5);
        f16x8 ml = ldfrag(WkL, l31 + 32 * ot, kt, g5);
        ah[ot] = MFMA(mh, hhi[kt], ah[ot]);
        al[ot] = MFMA(mh, hlo[kt], al[ot]);
        al[ot] = MFMA(ml, hhi[kt], al[ot]);
      }
    }
    int fk = 32 * w + l31;
    int sw = l7;
#pragma unroll
    for (int ot = 0; ot < 2; ++ot) {
#pragma unroll
      for (int rq = 0; rq < 4; ++rq) {
        int o0 = 32 * ot + 8 * rq + 4 * g5;
        float4 bb = *(const float4*)(bk + o0);
        float k0 = ah[ot][4 * rq + 0] + al[ot][4 * rq + 0] * RLO + bb.x;
        float k1 = ah[ot][4 * rq + 1] + al[ot][4 * rq + 1] * RLO + bb.y;
        float k2 = ah[ot][4 * rq + 2] + al[ot][4 * rq + 2] * RLO + bb.z;
        float k3 = ah[ot][4 * rq + 3] + al[ot][4 * rq + 3] * RLO + bb.w;
        u32 h01, l01, h23, l23;
        sp2(k0, k1, 512.f, &h01, &l01);
        sp2(k2, k3, 512.f, &h23, &l23);
        int ch = (4 * ot + rq) ^ sw;
        *(uint2*)(Khi + fk * KSTRIDE + ch * 16 + 8 * g5) = make_uint2(h01, h23);
        *(uint2*)(Klo + fk * KSTRIDE + ch * 16 + 8 * g5) = make_uint2(l01, l23);
      }
    }
  }

  // ---- V = (Wv split)(h split) + bv -> Vt single f16 (16B chunks) ----
  {
    f32x16 ah[2] = {}, al[2] = {};
#pragma unroll
    for (int kt = 0; kt < 4; ++kt) {
#pragma unroll
      for (int nt = 0; nt < 2; ++nt) {
        f16x8 mh = ldfrag(WvH, l31 + 32 * nt, kt, g5);
        f16x8 ml = ldfrag(WvL, l31 + 32 * nt, kt, g5);
        ah[nt] = MFMA(hhi[kt], mh, ah[nt]);
        al[nt] = MFMA(hlo[kt], mh, al[nt]);
        al[nt] = MFMA(hhi[kt], ml, al[nt]);
      }
    }
#pragma unroll
    for (int nt = 0; nt < 2; ++nt) {
      int hh = l31 + 32 * nt;
      float bvj = bv[hh];
      int sw = hh & 7;
#pragma unroll
      for (int rq = 0; rq < 4; ++rq) {
        float v0 = ah[nt][4 * rq + 0] + al[nt][4 * rq + 0] * RLO + bvj;
        float v1 = ah[nt][4 * rq + 1] + al[nt][4 * rq + 1] * RLO + bvj;
        float v2 = ah[nt][4 * rq + 2] + al[nt][4 * rq + 2] * RLO + bvj;
        float v3 = ah[nt][4 * rq + 3] + al[nt][4 * rq + 3] * RLO + bvj;
        int ch = (4 * w + rq) ^ sw;
        *(uint2*)(Vlds + hh * VSTRIDE + ch * 16 + 8 * g5) =
            make_uint2(pk2(v0, v1), pk2(v2, v3));
      }
    }
  }

  // ---- Q' = ((Wq split)(h split) + bq)*qs, split B-fragments in regs ----
  f16x8 qf[4], ql[4];
  {
    f32x16 ah[2] = {}, al[2] = {};
#pragma unroll
    for (int kt = 0; kt < 4; ++kt) {
#pragma unroll
      for (int ot = 0; ot < 2; ++ot) {
        f16x8 mh = ldfrag(WqH, l31 + 32 * ot, kt, g5);
        f16x8 ml = ldfrag(WqL, l31 + 32 * ot, kt, g5);
        ah[ot] = MFMA(mh, hhi[kt], ah[ot]);
        al[ot] = MFMA(mh, hlo[kt], al[ot]);
        al[ot] = MFMA(ml, hhi[kt], al[ot]);
      }
    }
    const float qs = 0.18033688011112042f;  // log2(e)/sqrt(64)
#pragma unroll
    for (int ot = 0; ot < 2; ++ot) {
#pragma unroll
      for (int rq = 0; rq < 4; ++rq) {
        int o0 = 32 * ot + 8 * rq + 4 * g5;
        float4 bb = *(const float4*)(bq + o0);
        ah[ot][4 * rq + 0] = (ah[ot][4 * rq + 0] + al[ot][4 * rq + 0] * RLO + bb.x) * qs;
        ah[ot][4 * rq + 1] = (ah[ot][4 * rq + 1] + al[ot][4 * rq + 1] * RLO + bb.y) * qs;
        ah[ot][4 * rq + 2] = (ah[ot][4 * rq + 2] + al[ot][4 * rq + 2] * RLO + bb.z) * qs;
        ah[ot][4 * rq + 3] = (ah[ot][4 * rq + 3] + al[ot][4 * rq + 3] * RLO + bb.w) * qs;
      }
    }
#pragma unroll
    for (int kt = 0; kt < 4; ++kt)
      xfrag2(ah[kt >> 1], kt & 1, g5, &qf[kt], &ql[kt], 512.f);
  }

  __syncthreads();

  const float alv = alp[0];
  const float btc0 = bt[l31], btc1 = bt[l31 + 32];
  const float g3v0 = g3[l31], g3v1 = g3[l31 + 32];
  const float b3v0 = b3[l31], b3v1 = b3[l31 + 32];
  u16* yb = yws + (size_t)b * 16384;

  // ---- E^T = (Khi+Klo/S)·(Qhi+Qlo/S)^T : D[fk][fq], fq = 32w + l31 ----
  f32x16 e[8];
#pragma unroll
  for (int m = 0; m < 8; ++m) {
    const char* krh = Khi + (l31 + 32 * m) * KSTRIDE;
    const char* krl = Klo + (l31 + 32 * m) * KSTRIDE;
    f32x16 eh = {}, em = {};
#pragma unroll
    for (int kt = 0; kt < 4; ++kt) {
      int ch = (2 * kt + g5) ^ l7;
      f16x8 kh = __builtin_bit_cast(f16x8, *(const uint4*)(krh + ch * 16));
      f16x8 kl = __builtin_bit_cast(f16x8, *(const uint4*)(krl + ch * 16));
      eh = MFMA(kh, qf[kt], eh);
      em = MFMA(kh, ql[kt], em);
      em = MFMA(kl, qf[kt], em);
    }
#pragma unroll
    for (int r = 0; r < 16; ++r) e[m][r] = eh[r] + em[r] * RLO;
  }
  // ---- softmax over fk ----
  float mx = -3.0e38f;
#pragma unroll
  for (int m = 0; m < 8; ++m)
#pragma unroll
    for (int r = 0; r < 16; ++r) mx = fmaxf(mx, e[m][r]);
  mx = fmaxf(mx, __shfl_xor(mx, 32));
  float s = 0.f;
#pragma unroll
  for (int m = 0; m < 8; ++m)
#pragma unroll
    for (int r = 0; r < 16; ++r) {
      float p = ex2(e[m][r] - mx);
      e[m][r] = p;
      s += p;
    }
  s += __shfl_xor(s, 32);
  float rcps = 1.0f / s;

  // ---- WV^T = Vt · P^T (P single f16 — post-softmax errors are relative) ----
  f32x16 wv0 = {}, wv1 = {};
#pragma unroll
  for (int kt = 0; kt < 16; ++kt) {
    f16x8 pf = xfrag(e[kt >> 1], kt & 1, g5);
    int ch = (2 * kt + g5) ^ l7;
    f16x8 vaf = __builtin_bit_cast(f16x8, *(const uint4*)(Vlds + l31 * VSTRIDE + ch * 16));
    wv0 = MFMA(vaf, pf, wv0);
    f16x8 vbf = __builtin_bit_cast(f16x8, *(const uint4*)(Vlds + (l31 + 32) * VSTRIDE + ch * 16));
    wv1 = MFMA(vbf, pf, wv1);
  }

  // ---- LN2 over h (apply softmax denom here) ----
  float s2 = 0.f, sq2 = 0.f;
#pragma unroll
  for (int r = 0; r < 16; ++r) {
    float a = wv0[r] * rcps; wv0[r] = a; s2 += a; sq2 += a * a;
    float c = wv1[r] * rcps; wv1[r] = c; s2 += c; sq2 += c * c;
  }
  s2 += __shfl_xor(s2, 32);
  sq2 += __shfl_xor(sq2, 32);
  float m2 = s2 * (1.f / 64.f);
  float v2 = sq2 * (1.f / 64.f) - m2 * m2;
  float rs2 = rsqrtf(v2 + 1e-5f);
#pragma unroll
  for (int at = 0; at < 2; ++at) {
#pragma unroll
    for (int rq = 0; rq < 4; ++rq) {
      int h0 = 32 * at + 8 * rq + 4 * g5;
      float4 gg = *(const float4*)(g2 + h0);
      float4 bb = *(const float4*)(b2 + h0);
      f32x16& a = at ? wv1 : wv0;
      a[4 * rq + 0] = (a[4 * rq + 0] - m2) * rs2 * gg.x + bb.x;
      a[4 * rq + 1] = (a[4 * rq + 1] - m2) * rs2 * gg.y + bb.y;
      a[4 * rq + 2] = (a[4 * rq + 2] - m2) * rs2 * gg.z + bb.z;
      a[4 * rq + 3] = (a[4 * rq + 3] - m2) * rs2 * gg.w + bb.w;
    }
  }
  f16x8 afh[4], afl[4];
  xfrag2(wv0, 0, g5, &afh[0], &afl[0], 1.f);
  xfrag2(wv0, 1, g5, &afh[1], &afl[1], 1.f);
  xfrag2(wv1, 0, g5, &afh[2], &afl[2], 1.f);
  xfrag2(wv1, 1, g5, &afh[3], &afl[3], 1.f);

  // ---- OUT = WVln · Wt^T : D[f][c] ----
  f32x16 o0 = {}, o1 = {};
#pragma unroll
  for (int kt = 0; kt < 4; ++kt) {
    f16x8 w0 = ldfrag(WtH, l31, kt, g5);
    f16x8 w1 = ldfrag(WtH, l31 + 32, kt, g5);
    o0 = MFMA(afh[kt], w0, o0);
    o0 = MFMA(afl[kt], w0, o0);
    o1 = MFMA(afh[kt], w1, o1);
    o1 = MFMA(afl[kt], w1, o1);
  }

  // ---- +bt, LN3 over c (red32 butterfly per row), PReLU, store y f16 ----
  const int fbase = 32 * w + 4 * g5;
#pragma unroll
  for (int r = 0; r < 16; ++r) {
    float v0 = o0[r] + btc0;
    float v1 = o1[r] + btc1;
    float S = red32(v0 + v1);
    float SQ = red32(v0 * v0 + v1 * v1);
    float m3 = S * (1.f / 64.f);
    float va = SQ * (1.f / 64.f) - m3 * m3;
    float rs3 = rsqrtf(va + 1e-5f);
    float y0 = (v0 - m3) * rs3 * g3v0 + b3v0;
    float y1 = (v1 - m3) * rs3 * g3v1 + b3v1;
    y0 = y0 >= 0.f ? y0 : alv * y0;
    y1 = y1 >= 0.f ? y1 : alv * y1;
    int f = fbase + (r & 3) + 8 * (r >> 2);
    u16* yp = yb + f * 64 + l31;
    yp[0] = f16b(y0);
    yp[32] = f16b(y1);
  }
}

// ---------------- K3: out[n,c,f,t] = inputs + y[b,f,c] (f32 out) ----------------
__global__ __launch_bounds__(256) void k_post(const float* __restrict__ inp,
                                              const u16* __restrict__ yws,
                                              float* __restrict__ out) {
  __shared__ float tile[64 * 66];
  const int bid = blockIdx.x;
  const int n = bid >> 10;
  const int rem = bid & 1023;
  const int f = rem >> 2;
  const int t0 = (rem & 3) << 6;
  const int tid = threadIdx.x;

  const int c2 = (tid & 31) * 2, tb = tid >> 5;
  const u32* src = (const u32*)yws;
#pragma unroll
  for (int k = 0; k < 8; ++k) {
    int t = tb + 8 * k;
    u32 v = src[((n * 256 + t0 + t) * 256 + f) * 32 + (tid & 31)];
    float2 p = up2(v);
    tile[t * 66 + c2] = p.x;
    tile[t * 66 + c2 + 1] = p.y;
  }
  __syncthreads();
  const int tt = tid & 63, cb = tid >> 6;
#pragma unroll
  for (int k = 0; k < 16; ++k) {
    int c = cb * 16 + k;
    size_t idx = ((size_t)(n * 64 + c) * 256 + f) * 256 + t0 + tt;
    out[idx] = inp[idx] + tile[tt * 66 + c];
  }
}

extern "C" void kernel_launch(void* const* d_in, const int* in_sizes, int n_in,
                              void* d_out, int out_size, void* d_ws, size_t ws_size,
                              hipStream_t stream) {
  const float* inp = (const float*)d_in[0];
  const float* Wq = (const float*)d_in[1];
  const float* bq = (const float*)d_in[2];
  const float* Wk = (const float*)d_in[3];
  const float* bk = (const float*)d_in[4];
  const float* Wv = (const float*)d_in[5];
  const float* bv = (const float*)d_in[6];
  const float* g1 = (const float*)d_in[7];
  const float* b1 = (const float*)d_in[8];
  const float* g2 = (const float*)d_in[9];
  const float* b2 = (const float*)d_in[10];
  const float* Wt = (const float*)d_in[11];
  const float* bt = (const float*)d_in[12];
  const float* g3 = (const float*)d_in[13];
  const float* b3 = (const float*)d_in[14];
  const float* al = (const float*)d_in[15];
  float* xstage = (float*)d_out;  // x f32 [b][f][c] = 128 MiB (k_post overwrites)
  u16* yws = (u16*)d_ws;          // y f16 [b][f][c] = 64 MiB

  (void)hipFuncSetAttribute((const void*)k_attn,
                            hipFuncAttributeMaxDynamicSharedMemorySize, 160256);
  k_pre32<<<8192, 256, 0, stream>>>(inp, xstage);
  k_attn<<<2048, 512, 160256, stream>>>(xstage, yws, Wq, bq, Wk, bk, Wv, bv,
                                        g1, b1, g2, b2, Wt, bt, g3, b3, al);
  k_post<<<8192, 256, 0, stream>>>(inp, yws, (float*)d_out);
}

// Round 16
// 286.315 us; speedup vs baseline: 1.4195x; 1.4195x over previous
//
#include <hip/hip_runtime.h>

typedef _Float16 f16;
typedef _Float16 f16x2 __attribute__((ext_vector_type(2)));
typedef _Float16 f16x8 __attribute__((ext_vector_type(8)));
typedef float f32x16 __attribute__((ext_vector_type(16)));
typedef unsigned int u32;
typedef unsigned short u16;

#define MFMA(a, b, c) __builtin_amdgcn_mfma_f32_32x32x16_f16((a), (b), (c), 0, 0, 0)

// RNE f16 pack
__device__ __forceinline__ u32 pk2(float a, float b) {
  union { f16x2 h; u32 u; } x;
  x.h[0] = (f16)a; x.h[1] = (f16)b;
  return x.u;
}
__device__ __forceinline__ float2 up2(u32 u) {
  union { u32 u_; f16x2 h; } x; x.u_ = u;
  return make_float2((float)x.h[0], (float)x.h[1]);
}
__device__ __forceinline__ f16x8 mk8(u32 a, u32 b, u32 c, u32 d) {
  union { u32 u[4]; f16x8 v; } x;
  x.u[0] = a; x.u[1] = b; x.u[2] = c; x.u[3] = d;
  return x.v;
}
__device__ __forceinline__ u16 f16b(float v) {
  union { f16 h; u16 u; } x; x.h = (f16)v; return x.u;
}
__device__ __forceinline__ float ex2(float x) {
#if __has_builtin(__builtin_amdgcn_exp2f)
  return __builtin_amdgcn_exp2f(x);
#else
  return exp2f(x);
#endif
}

// RNE pack pair + scaled residual (hi unbiased half-ulp; lo absorbs it exactly).
__device__ __forceinline__ void sp2(float a, float b, float S, u32* hi, u32* lo) {
  union { f16x2 h; u32 u; } xh, xl;
  xh.h[0] = (f16)a; xh.h[1] = (f16)b;
  float ra = (a - (float)xh.h[0]) * S;
  float rb = (b - (float)xh.h[1]) * S;
  xl.h[0] = (f16)ra; xl.h[1] = (f16)rb;
  *hi = xh.u; *lo = xl.u;
}

template<int CTRL>
__device__ __forceinline__ float dpp_add(float v) {
  int t = __builtin_amdgcn_update_dpp(0, __builtin_bit_cast(int, v), CTRL, 0xF, 0xF, true);
  return v + __builtin_bit_cast(float, t);
}
// sum over each 32-lane half
__device__ __forceinline__ float red32(float v) {
  v = dpp_add<0xB1>(v);   // xor 1
  v = dpp_add<0x4E>(v);   // xor 2
  v = dpp_add<0x141>(v);  // xor 7 (row_half_mirror)
  v = dpp_add<0x140>(v);  // xor 15 (row_mirror)
  int sw = __builtin_amdgcn_ds_swizzle(__builtin_bit_cast(int, v), 0x401F); // xor 16
  return v + __builtin_bit_cast(float, sw);
}

// D-layout f32x16 -> single A/B fragment (k = 16*kt1 + 8*g5 + e), RNE.
__device__ __forceinline__ f16x8 xfrag(const f32x16 a, int kt1, int g5) {
  u32 u0, u1, u2, u3;
  if (kt1 == 0) {
    u0 = pk2(a[0], a[1]);   u1 = pk2(a[2], a[3]);
    u2 = pk2(a[4], a[5]);   u3 = pk2(a[6], a[7]);
  } else {
    u0 = pk2(a[8], a[9]);   u1 = pk2(a[10], a[11]);
    u2 = pk2(a[12], a[13]); u3 = pk2(a[14], a[15]);
  }
  u32 s0 = (u32)__shfl_xor((int)u0, 32);
  u32 s1 = (u32)__shfl_xor((int)u1, 32);
  u32 s2 = (u32)__shfl_xor((int)u2, 32);
  u32 s3 = (u32)__shfl_xor((int)u3, 32);
  u32 r0 = g5 ? s2 : u0;
  u32 r1 = g5 ? s3 : u1;
  u32 r2 = g5 ? u2 : s0;
  u32 r3 = g5 ? u3 : s1;
  return mk8(r0, r1, r2, r3);
}

// split hi/lo (lo scaled by S) variant
__device__ __forceinline__ void xfrag2(const f32x16 a, int kt1, int g5,
                                       f16x8* hi, f16x8* lo, float S) {
  u32 uh[4], ul[4];
#pragma unroll
  for (int j = 0; j < 4; ++j) {
    float v0 = kt1 ? a[8 + 2 * j] : a[2 * j];
    float v1 = kt1 ? a[9 + 2 * j] : a[2 * j + 1];
    sp2(v0, v1, S, &uh[j], &ul[j]);
  }
  u32 sh[4], sl[4];
#pragma unroll
  for (int j = 0; j < 4; ++j) {
    sh[j] = (u32)__shfl_xor((int)uh[j], 32);
    sl[j] = (u32)__shfl_xor((int)ul[j], 32);
  }
  *hi = mk8(g5 ? sh[2] : uh[0], g5 ? sh[3] : uh[1],
            g5 ? uh[2] : sh[0], g5 ? uh[3] : sh[1]);
  *lo = mk8(g5 ? sl[2] : ul[0], g5 ? sl[3] : ul[1],
            g5 ? ul[2] : sl[0], g5 ? ul[3] : sl[1]);
}

// W-plane read: 8B-granule, XOR-(row&15) — R11-proven layout.
__device__ __forceinline__ f16x8 ldfrag(const char* plane, int row, int kt, int g5) {
  int s = row & 15;
  int c8 = 4 * kt + 2 * g5;
  uint2 a = *(const uint2*)(plane + row * 128 + ((c8) ^ s) * 8);
  uint2 b = *(const uint2*)(plane + row * 128 + ((c8 + 1) ^ s) * 8);
  return mk8(a.x, a.y, b.x, b.y);
}

// ---------------- K1: [N,C,F,T] f32 -> x[B=n*256+t][F][C] f32 (into d_out) ----
__global__ __launch_bounds__(256) void k_pre32(const float* __restrict__ inp,
                                               float* __restrict__ xws) {
  __shared__ float tile[64 * 65];
  const int bid = blockIdx.x;
  const int n = bid >> 10;
  const int rem = bid & 1023;
  const int f = rem >> 2;
  const int t0 = (rem & 3) << 6;
  const int tid = threadIdx.x;

  const int tt = tid & 63, cb = tid >> 6;
  const float* src = inp + ((size_t)n * 64 * 256 + f) * 256 + t0;
#pragma unroll
  for (int k = 0; k < 16; ++k) {
    int c = cb * 16 + k;
    tile[c * 65 + tt] = src[(size_t)c * 65536 + tt];
  }
  __syncthreads();
  const int c2 = (tid & 31) * 2, tb = tid >> 5;
#pragma unroll
  for (int k = 0; k < 8; ++k) {
    int t = tb + 8 * k;
    float2 v = make_float2(tile[c2 * 65 + t], tile[(c2 + 1) * 65 + t]);
    *(float2*)(xws + ((size_t)(n * 256 + t0 + t) * 256 + f) * 64 + c2) = v;
  }
}

// ---------------- K2: fused LN1+QKV+attn+LN2+proj+LN3+PReLU ----------------
// 512 threads = 8 waves; wave w owns F-rows [32w, 32w+32).
// K/V: 16B-chunk xor-7, ALIGNED 128/512B strides (R14-proven; padded strides
// broke b128 alignment and cost +100us in R15). P single-f16 (R15-proven).
__global__ __launch_bounds__(512, 2) void k_attn(
    const float* __restrict__ xg,  // x f32 [b][f][c] (staged in d_out)
    u16* __restrict__ yws,         // y f16 out
    const float* __restrict__ Wq, const float* __restrict__ bq,
    const float* __restrict__ Wk, const float* __restrict__ bk,
    const float* __restrict__ Wv, const float* __restrict__ bv,
    const float* __restrict__ g1, const float* __restrict__ b1,
    const float* __restrict__ g2, const float* __restrict__ b2,
    const float* __restrict__ Wt, const float* __restrict__ bt,
    const float* __restrict__ g3, const float* __restrict__ b3,
    const float* __restrict__ alp) {
  extern __shared__ char smem[];
  char* Khi = smem;                  // K hi f16 [256][128B], 16B-chunk xor-7
  char* Klo = smem + 32768;          // K residual*512
  char* Vlds = smem + 65536;         // Vt f16 [64][512B], 16B-chunk xor-7
  char* WkH = smem + 98304;          // W planes: [64 rows][16 granules], xor-15
  char* WkL = smem + 106496;
  char* WvH = smem + 114688;
  char* WvL = smem + 122880;
  char* WqH = smem + 131072;
  char* WqL = smem + 139264;
  char* WtH = smem + 147456;         // -> total 155648 B

  const int tid = threadIdx.x;
  const int w = tid >> 6;          // 0..7
  const int lane = tid & 63;
  const int l31 = lane & 31;
  const int g5 = lane >> 5;
  const int l7 = l31 & 7;
  const int b = blockIdx.x;
  const float* xb = xg + (size_t)b * 16384;
  const float RLO = 1.f / 512.f;

  // ---- issue x loads early (latency hides under W-prep) ----
  float xv[32];
  {
    int f = 32 * w + l31;
#pragma unroll
    for (int kt = 0; kt < 4; ++kt) {
      float4 a = *(const float4*)(xb + f * 64 + 16 * kt + 8 * g5);
      float4 c = *(const float4*)(xb + f * 64 + 16 * kt + 8 * g5 + 4);
      xv[kt * 8 + 0] = a.x; xv[kt * 8 + 1] = a.y;
      xv[kt * 8 + 2] = a.z; xv[kt * 8 + 3] = a.w;
      xv[kt * 8 + 4] = c.x; xv[kt * 8 + 5] = c.y;
      xv[kt * 8 + 6] = c.z; xv[kt * 8 + 7] = c.w;
    }
  }

  // ---- Phase 0: cooperative W -> LDS split-pack (R11 8B-granule scheme) ----
  {
    const int prow = tid >> 3, pc = tid & 7;
    const int ps = prow & 15;
    const int pha = (2 * pc) ^ ps, phb = (2 * pc + 1) ^ ps;
    const size_t off = (size_t)prow * 64 + pc * 8;
    {
      float4 a = *(const float4*)(Wk + off);
      float4 c = *(const float4*)(Wk + off + 4);
      u32 h0, l0, h1, l1, h2, l2, h3, l3;
      sp2(a.x, a.y, 512.f, &h0, &l0); sp2(a.z, a.w, 512.f, &h1, &l1);
      sp2(c.x, c.y, 512.f, &h2, &l2); sp2(c.z, c.w, 512.f, &h3, &l3);
      *(uint2*)(WkH + prow * 128 + pha * 8) = make_uint2(h0, h1);
      *(uint2*)(WkH + prow * 128 + phb * 8) = make_uint2(h2, h3);
      *(uint2*)(WkL + prow * 128 + pha * 8) = make_uint2(l0, l1);
      *(uint2*)(WkL + prow * 128 + phb * 8) = make_uint2(l2, l3);
    }
    {
      float4 a = *(const float4*)(Wv + off);
      float4 c = *(const float4*)(Wv + off + 4);
      u32 h0, l0, h1, l1, h2, l2, h3, l3;
      sp2(a.x, a.y, 512.f, &h0, &l0); sp2(a.z, a.w, 512.f, &h1, &l1);
      sp2(c.x, c.y, 512.f, &h2, &l2); sp2(c.z, c.w, 512.f, &h3, &l3);
      *(uint2*)(WvH + prow * 128 + pha * 8) = make_uint2(h0, h1);
      *(uint2*)(WvH + prow * 128 + phb * 8) = make_uint2(h2, h3);
      *(uint2*)(WvL + prow * 128 + pha * 8) = make_uint2(l0, l1);
      *(uint2*)(WvL + prow * 128 + phb * 8) = make_uint2(l2, l3);
    }
    {
      float4 a = *(const float4*)(Wq + off);
      float4 c = *(const float4*)(Wq + off + 4);
      u32 h0, l0, h1, l1, h2, l2, h3, l3;
      sp2(a.x, a.y, 512.f, &h0, &l0); sp2(a.z, a.w, 512.f, &h1, &l1);
      sp2(c.x, c.y, 512.f, &h2, &l2); sp2(c.z, c.w, 512.f, &h3, &l3);
      *(uint2*)(WqH + prow * 128 + pha * 8) = make_uint2(h0, h1);
      *(uint2*)(WqH + prow * 128 + phb * 8) = make_uint2(h2, h3);
      *(uint2*)(WqL + prow * 128 + pha * 8) = make_uint2(l0, l1);
      *(uint2*)(WqL + prow * 128 + phb * 8) = make_uint2(l2, l3);
    }
    {
      float4 a = *(const float4*)(Wt + off);
      float4 c = *(const float4*)(Wt + off + 4);
      *(uint2*)(WtH + prow * 128 + pha * 8) = make_uint2(pk2(a.x, a.y), pk2(a.z, a.w));
      *(uint2*)(WtH + prow * 128 + phb * 8) = make_uint2(pk2(c.x, c.y), pk2(c.z, c.w));
    }
  }
  __syncthreads();

  // ---- LN1 (f32) -> split h fragments ----
  f16x8 hhi[4], hlo[4];
  {
    float s = 0.f, sq = 0.f;
#pragma unroll
    for (int i = 0; i < 32; ++i) { s += xv[i]; sq += xv[i] * xv[i]; }
    s += __shfl_xor(s, 32);
    sq += __shfl_xor(sq, 32);
    float mean = s * (1.f / 64.f);
    float var = sq * (1.f / 64.f) - mean * mean;
    float rs = rsqrtf(var + 1e-5f);
#pragma unroll
    for (int kt = 0; kt < 4; ++kt) {
      int c0 = 16 * kt + 8 * g5;
      u32 ph[4], pl[4];
#pragma unroll
      for (int j = 0; j < 4; ++j) {
        float v0 = (xv[kt * 8 + 2 * j] - mean) * rs * g1[c0 + 2 * j] + b1[c0 + 2 * j];
        float v1 = (xv[kt * 8 + 2 * j + 1] - mean) * rs * g1[c0 + 2 * j + 1] + b1[c0 + 2 * j + 1];
        sp2(v0, v1, 512.f, &ph[j], &pl[j]);
      }
      hhi[kt] = mk8(ph[0], ph[1], ph[2], ph[3]);
      hlo[kt] = mk8(pl[0], pl[1], pl[2], pl[3]);
    }
  }

  // ---- K = (Wk split)(h split) + bk -> split store Khi/Klo (16B chunks) ----
  {
    f32x16 ah[2] = {}, al[2] = {};
#pragma unroll
    for (int kt = 0; kt < 4; ++kt) {
#pragma unroll
      for (int ot = 0; ot < 2; ++ot) {
        f16x8 mh = ldfrag(WkH, l31 + 32 * ot, kt, g5);
        f16x8 ml = ldfrag(WkL, l31 + 32 * ot, kt, g5);
        ah[ot] = MFMA(mh, hhi[kt], ah[ot]);
        al[ot] = MFMA(mh, hlo[kt], al[ot]);
        al[ot] = MFMA(ml, hhi[kt], al[ot]);
      }
    }
    int fk = 32 * w + l31;
    int sw = l7;
#pragma unroll
    for (int ot = 0; ot < 2; ++ot) {
#pragma unroll
      for (int rq = 0; rq < 4; ++rq) {
        int o0 = 32 * ot + 8 * rq + 4 * g5;
        float4 bb = *(const float4*)(bk + o0);
        float k0 = ah[ot][4 * rq + 0] + al[ot][4 * rq + 0] * RLO + bb.x;
        float k1 = ah[ot][4 * rq + 1] + al[ot][4 * rq + 1] * RLO + bb.y;
        float k2 = ah[ot][4 * rq + 2] + al[ot][4 * rq + 2] * RLO + bb.z;
        float k3 = ah[ot][4 * rq + 3] + al[ot][4 * rq + 3] * RLO + bb.w;
        u32 h01, l01, h23, l23;
        sp2(k0, k1, 512.f, &h01, &l01);
        sp2(k2, k3, 512.f, &h23, &l23);
        int ch = (4 * ot + rq) ^ sw;
        *(uint2*)(Khi + fk * 128 + ch * 16 + 8 * g5) = make_uint2(h01, h23);
        *(uint2*)(Klo + fk * 128 + ch * 16 + 8 * g5) = make_uint2(l01, l23);
      }
    }
  }

  // ---- V = (Wv split)(h split) + bv -> Vt single f16 (16B chunks) ----
  {
    f32x16 ah[2] = {}, al[2] = {};
#pragma unroll
    for (int kt = 0; kt < 4; ++kt) {
#pragma unroll
      for (int nt = 0; nt < 2; ++nt) {
        f16x8 mh = ldfrag(WvH, l31 + 32 * nt, kt, g5);
        f16x8 ml = ldfrag(WvL, l31 + 32 * nt, kt, g5);
        ah[nt] = MFMA(hhi[kt], mh, ah[nt]);
        al[nt] = MFMA(hlo[kt], mh, al[nt]);
        al[nt] = MFMA(hhi[kt], ml, al[nt]);
      }
    }
#pragma unroll
    for (int nt = 0; nt < 2; ++nt) {
      int hh = l31 + 32 * nt;
      float bvj = bv[hh];
      int sw = hh & 7;
#pragma unroll
      for (int rq = 0; rq < 4; ++rq) {
        float v0 = ah[nt][4 * rq + 0] + al[nt][4 * rq + 0] * RLO + bvj;
        float v1 = ah[nt][4 * rq + 1] + al[nt][4 * rq + 1] * RLO + bvj;
        float v2 = ah[nt][4 * rq + 2] + al[nt][4 * rq + 2] * RLO + bvj;
        float v3 = ah[nt][4 * rq + 3] + al[nt][4 * rq + 3] * RLO + bvj;
        int ch = (4 * w + rq) ^ sw;
        *(uint2*)(Vlds + hh * 512 + ch * 16 + 8 * g5) =
            make_uint2(pk2(v0, v1), pk2(v2, v3));
      }
    }
  }

  // ---- Q' = ((Wq split)(h split) + bq)*qs, split B-fragments in regs ----
  f16x8 qf[4], ql[4];
  {
    f32x16 ah[2] = {}, al[2] = {};
#pragma unroll
    for (int kt = 0; kt < 4; ++kt) {
#pragma unroll
      for (int ot = 0; ot < 2; ++ot) {
        f16x8 mh = ldfrag(WqH, l31 + 32 * ot, kt, g5);
        f16x8 ml = ldfrag(WqL, l31 + 32 * ot, kt, g5);
        ah[ot] = MFMA(mh, hhi[kt], ah[ot]);
        al[ot] = MFMA(mh, hlo[kt], al[ot]);
        al[ot] = MFMA(ml, hhi[kt], al[ot]);
      }
    }
    const float qs = 0.18033688011112042f;  // log2(e)/sqrt(64)
#pragma unroll
    for (int ot = 0; ot < 2; ++ot) {
#pragma unroll
      for (int rq = 0; rq < 4; ++rq) {
        int o0 = 32 * ot + 8 * rq + 4 * g5;
        float4 bb = *(const float4*)(bq + o0);
        ah[ot][4 * rq + 0] = (ah[ot][4 * rq + 0] + al[ot][4 * rq + 0] * RLO + bb.x) * qs;
        ah[ot][4 * rq + 1] = (ah[ot][4 * rq + 1] + al[ot][4 * rq + 1] * RLO + bb.y) * qs;
        ah[ot][4 * rq + 2] = (ah[ot][4 * rq + 2] + al[ot][4 * rq + 2] * RLO + bb.z) * qs;
        ah[ot][4 * rq + 3] = (ah[ot][4 * rq + 3] + al[ot][4 * rq + 3] * RLO + bb.w) * qs;
      }
    }
#pragma unroll
    for (int kt = 0; kt < 4; ++kt)
      xfrag2(ah[kt >> 1], kt & 1, g5, &qf[kt], &ql[kt], 512.f);
  }

  __syncthreads();

  const float alv = alp[0];
  const float btc0 = bt[l31], btc1 = bt[l31 + 32];
  const float g3v0 = g3[l31], g3v1 = g3[l31 + 32];
  const float b3v0 = b3[l31], b3v1 = b3[l31 + 32];
  u16* yb = yws + (size_t)b * 16384;

  // ---- E^T = (Khi+Klo/S)·(Qhi+Qlo/S)^T : D[fk][fq], fq = 32w + l31 ----
  f32x16 e[8];
#pragma unroll
  for (int m = 0; m < 8; ++m) {
    const char* krh = Khi + (l31 + 32 * m) * 128;
    const char* krl = Klo + (l31 + 32 * m) * 128;
    f32x16 eh = {}, em = {};
#pragma unroll
    for (int kt = 0; kt < 4; ++kt) {
      int ch = (2 * kt + g5) ^ l7;
      f16x8 kh = __builtin_bit_cast(f16x8, *(const uint4*)(krh + ch * 16));
      f16x8 kl = __builtin_bit_cast(f16x8, *(const uint4*)(krl + ch * 16));
      eh = MFMA(kh, qf[kt], eh);
      em = MFMA(kh, ql[kt], em);
      em = MFMA(kl, qf[kt], em);
    }
#pragma unroll
    for (int r = 0; r < 16; ++r) e[m][r] = eh[r] + em[r] * RLO;
  }
  // ---- softmax over fk ----
  float mx = -3.0e38f;
#pragma unroll
  for (int m = 0; m < 8; ++m)
#pragma unroll
    for (int r = 0; r < 16; ++r) mx = fmaxf(mx, e[m][r]);
  mx = fmaxf(mx, __shfl_xor(mx, 32));
  float s = 0.f;
#pragma unroll
  for (int m = 0; m < 8; ++m)
#pragma unroll
    for (int r = 0; r < 16; ++r) {
      float p = ex2(e[m][r] - mx);
      e[m][r] = p;
      s += p;
    }
  s += __shfl_xor(s, 32);
  float rcps = 1.0f / s;

  // ---- WV^T = Vt · P^T (P single f16 — R15-proven) ----
  f32x16 wv0 = {}, wv1 = {};
#pragma unroll
  for (int kt = 0; kt < 16; ++kt) {
    f16x8 pf = xfrag(e[kt >> 1], kt & 1, g5);
    int ch = (2 * kt + g5) ^ l7;
    f16x8 vaf = __builtin_bit_cast(f16x8, *(const uint4*)(Vlds + l31 * 512 + ch * 16));
    wv0 = MFMA(vaf, pf, wv0);
    f16x8 vbf = __builtin_bit_cast(f16x8, *(const uint4*)(Vlds + (l31 + 32) * 512 + ch * 16));
    wv1 = MFMA(vbf, pf, wv1);
  }

  // ---- LN2 over h (apply softmax denom here) ----
  float s2 = 0.f, sq2 = 0.f;
#pragma unroll
  for (int r = 0; r < 16; ++r) {
    float a = wv0[r] * rcps; wv0[r] = a; s2 += a; sq2 += a * a;
    float c = wv1[r] * rcps; wv1[r] = c; s2 += c; sq2 += c * c;
  }
  s2 += __shfl_xor(s2, 32);
  sq2 += __shfl_xor(sq2, 32);
  float m2 = s2 * (1.f / 64.f);
  float v2 = sq2 * (1.f / 64.f) - m2 * m2;
  float rs2 = rsqrtf(v2 + 1e-5f);
#pragma unroll
  for (int at = 0; at < 2; ++at) {
#pragma unroll
    for (int rq = 0; rq < 4; ++rq) {
      int h0 = 32 * at + 8 * rq + 4 * g5;
      float4 gg = *(const float4*)(g2 + h0);
      float4 bb = *(const float4*)(b2 + h0);
      f32x16& a = at ? wv1 : wv0;
      a[4 * rq + 0] = (a[4 * rq + 0] - m2) * rs2 * gg.x + bb.x;
      a[4 * rq + 1] = (a[4 * rq + 1] - m2) * rs2 * gg.y + bb.y;
      a[4 * rq + 2] = (a[4 * rq + 2] - m2) * rs2 * gg.z + bb.z;
      a[4 * rq + 3] = (a[4 * rq + 3] - m2) * rs2 * gg.w + bb.w;
    }
  }
  f16x8 afh[4], afl[4];
  xfrag2(wv0, 0, g5, &afh[0], &afl[0], 1.f);
  xfrag2(wv0, 1, g5, &afh[1], &afl[1], 1.f);
  xfrag2(wv1, 0, g5, &afh[2], &afl[2], 1.f);
  xfrag2(wv1, 1, g5, &afh[3], &afl[3], 1.f);

  // ---- OUT = WVln · Wt^T : D[f][c] ----
  f32x16 o0 = {}, o1 = {};
#pragma unroll
  for (int kt = 0; kt < 4; ++kt) {
    f16x8 w0 = ldfrag(WtH, l31, kt, g5);
    f16x8 w1 = ldfrag(WtH, l31 + 32, kt, g5);
    o0 = MFMA(afh[kt], w0, o0);
    o0 = MFMA(afl[kt], w0, o0);
    o1 = MFMA(afh[kt], w1, o1);
    o1 = MFMA(afl[kt], w1, o1);
  }

  // ---- +bt, LN3 over c (red32 butterfly per row), PReLU, store y f16 ----
  const int fbase = 32 * w + 4 * g5;
#pragma unroll
  for (int r = 0; r < 16; ++r) {
    float v0 = o0[r] + btc0;
    float v1 = o1[r] + btc1;
    float S = red32(v0 + v1);
    float SQ = red32(v0 * v0 + v1 * v1);
    float m3 = S * (1.f / 64.f);
    float va = SQ * (1.f / 64.f) - m3 * m3;
    float rs3 = rsqrtf(va + 1e-5f);
    float y0 = (v0 - m3) * rs3 * g3v0 + b3v0;
    float y1 = (v1 - m3) * rs3 * g3v1 + b3v1;
    y0 = y0 >= 0.f ? y0 : alv * y0;
    y1 = y1 >= 0.f ? y1 : alv * y1;
    int f = fbase + (r & 3) + 8 * (r >> 2);
    u16* yp = yb + f * 64 + l31;
    yp[0] = f16b(y0);
    yp[32] = f16b(y1);
  }
}

// ---------------- K3: out[n,c,f,t] = inputs + y[b,f,c] (f32 out) ----------------
__global__ __launch_bounds__(256) void k_post(const float* __restrict__ inp,
                                              const u16* __restrict__ yws,
                                              float* __restrict__ out) {
  __shared__ float tile[64 * 66];
  const int bid = blockIdx.x;
  const int n = bid >> 10;
  const int rem = bid & 1023;
  const int f = rem >> 2;
  const int t0 = (rem & 3) << 6;
  const int tid = threadIdx.x;

  const int c2 = (tid & 31) * 2, tb = tid >> 5;
  const u32* src = (const u32*)yws;
#pragma unroll
  for (int k = 0; k < 8; ++k) {
    int t = tb + 8 * k;
    u32 v = src[((n * 256 + t0 + t) * 256 + f) * 32 + (tid & 31)];
    float2 p = up2(v);
    tile[t * 66 + c2] = p.x;
    tile[t * 66 + c2 + 1] = p.y;
  }
  __syncthreads();
  const int tt = tid & 63, cb = tid >> 6;
#pragma unroll
  for (int k = 0; k < 16; ++k) {
    int c = cb * 16 + k;
    size_t idx = ((size_t)(n * 64 + c) * 256 + f) * 256 + t0 + tt;
    out[idx] = inp[idx] + tile[tt * 66 + c];
  }
}

extern "C" void kernel_launch(void* const* d_in, const int* in_sizes, int n_in,
                              void* d_out, int out_size, void* d_ws, size_t ws_size,
                              hipStream_t stream) {
  const float* inp = (const float*)d_in[0];
  const float* Wq = (const float*)d_in[1];
  const float* bq = (const float*)d_in[2];
  const float* Wk = (const float*)d_in[3];
  const float* bk = (const float*)d_in[4];
  const float* Wv = (const float*)d_in[5];
  const float* bv = (const float*)d_in[6];
  const float* g1 = (const float*)d_in[7];
  const float* b1 = (const float*)d_in[8];
  const float* g2 = (const float*)d_in[9];
  const float* b2 = (const float*)d_in[10];
  const float* Wt = (const float*)d_in[11];
  const float* bt = (const float*)d_in[12];
  const float* g3 = (const float*)d_in[13];
  const float* b3 = (const float*)d_in[14];
  const float* al = (const float*)d_in[15];
  float* xstage = (float*)d_out;  // x f32 [b][f][c] = 128 MiB (k_post overwrites)
  u16* yws = (u16*)d_ws;          // y f16 [b][f][c] = 64 MiB

  (void)hipFuncSetAttribute((const void*)k_attn,
                            hipFuncAttributeMaxDynamicSharedMemorySize, 155648);
  k_pre32<<<8192, 256, 0, stream>>>(inp, xstage);
  k_attn<<<2048, 512, 155648, stream>>>(xstage, yws, Wq, bq, Wk, bk, Wv, bv,
                                        g1, b1, g2, b2, Wt, bt, g3, b3, al);
  k_post<<<8192, 256, 0, stream>>>(inp, yws, (float*)d_out);
}

// Round 18
// 278.503 us; speedup vs baseline: 1.4593x; 1.0280x over previous
//
#include <hip/hip_runtime.h>

typedef _Float16 f16;
typedef _Float16 f16x2 __attribute__((ext_vector_type(2)));
typedef _Float16 f16x8 __attribute__((ext_vector_type(8)));
typedef float f32x16 __attribute__((ext_vector_type(16)));
typedef unsigned int u32;
typedef unsigned short u16;

#define MFMA(a, b, c) __builtin_amdgcn_mfma_f32_32x32x16_f16((a), (b), (c), 0, 0, 0)

// RNE f16 pack
__device__ __forceinline__ u32 pk2(float a, float b) {
  union { f16x2 h; u32 u; } x;
  x.h[0] = (f16)a; x.h[1] = (f16)b;
  return x.u;
}
__device__ __forceinline__ float2 up2(u32 u) {
  union { u32 u_; f16x2 h; } x; x.u_ = u;
  return make_float2((float)x.h[0], (float)x.h[1]);
}
__device__ __forceinline__ f16x8 mk8(u32 a, u32 b, u32 c, u32 d) {
  union { u32 u[4]; f16x8 v; } x;
  x.u[0] = a; x.u[1] = b; x.u[2] = c; x.u[3] = d;
  return x.v;
}
__device__ __forceinline__ u16 f16b(float v) {
  union { f16 h; u16 u; } x; x.h = (f16)v; return x.u;
}
__device__ __forceinline__ float ex2(float x) {
#if __has_builtin(__builtin_amdgcn_exp2f)
  return __builtin_amdgcn_exp2f(x);
#else
  return exp2f(x);
#endif
}

// RNE pack pair + scaled residual (hi unbiased half-ulp; lo absorbs it exactly).
__device__ __forceinline__ void sp2(float a, float b, float S, u32* hi, u32* lo) {
  union { f16x2 h; u32 u; } xh, xl;
  xh.h[0] = (f16)a; xh.h[1] = (f16)b;
  float ra = (a - (float)xh.h[0]) * S;
  float rb = (b - (float)xh.h[1]) * S;
  xl.h[0] = (f16)ra; xl.h[1] = (f16)rb;
  *hi = xh.u; *lo = xl.u;
}

template<int CTRL>
__device__ __forceinline__ float dpp_add(float v) {
  int t = __builtin_amdgcn_update_dpp(0, __builtin_bit_cast(int, v), CTRL, 0xF, 0xF, true);
  return v + __builtin_bit_cast(float, t);
}
// sum over each 32-lane half
__device__ __forceinline__ float red32(float v) {
  v = dpp_add<0xB1>(v);   // xor 1
  v = dpp_add<0x4E>(v);   // xor 2
  v = dpp_add<0x141>(v);  // xor 7 (row_half_mirror)
  v = dpp_add<0x140>(v);  // xor 15 (row_mirror)
  int sw = __builtin_amdgcn_ds_swizzle(__builtin_bit_cast(int, v), 0x401F); // xor 16
  return v + __builtin_bit_cast(float, sw);
}

// D-layout f32x16 -> single A/B fragment (k = 16*kt1 + 8*g5 + e), RNE.
__device__ __forceinline__ f16x8 xfrag(const f32x16 a, int kt1, int g5) {
  u32 u0, u1, u2, u3;
  if (kt1 == 0) {
    u0 = pk2(a[0], a[1]);   u1 = pk2(a[2], a[3]);
    u2 = pk2(a[4], a[5]);   u3 = pk2(a[6], a[7]);
  } else {
    u0 = pk2(a[8], a[9]);   u1 = pk2(a[10], a[11]);
    u2 = pk2(a[12], a[13]); u3 = pk2(a[14], a[15]);
  }
  u32 s0 = (u32)__shfl_xor((int)u0, 32);
  u32 s1 = (u32)__shfl_xor((int)u1, 32);
  u32 s2 = (u32)__shfl_xor((int)u2, 32);
  u32 s3 = (u32)__shfl_xor((int)u3, 32);
  u32 r0 = g5 ? s2 : u0;
  u32 r1 = g5 ? s3 : u1;
  u32 r2 = g5 ? u2 : s0;
  u32 r3 = g5 ? u3 : s1;
  return mk8(r0, r1, r2, r3);
}

// split hi/lo (lo scaled by S) variant
__device__ __forceinline__ void xfrag2(const f32x16 a, int kt1, int g5,
                                       f16x8* hi, f16x8* lo, float S) {
  u32 uh[4], ul[4];
#pragma unroll
  for (int j = 0; j < 4; ++j) {
    float v0 = kt1 ? a[8 + 2 * j] : a[2 * j];
    float v1 = kt1 ? a[9 + 2 * j] : a[2 * j + 1];
    sp2(v0, v1, S, &uh[j], &ul[j]);
  }
  u32 sh[4], sl[4];
#pragma unroll
  for (int j = 0; j < 4; ++j) {
    sh[j] = (u32)__shfl_xor((int)uh[j], 32);
    sl[j] = (u32)__shfl_xor((int)ul[j], 32);
  }
  *hi = mk8(g5 ? sh[2] : uh[0], g5 ? sh[3] : uh[1],
            g5 ? uh[2] : sh[0], g5 ? uh[3] : sh[1]);
  *lo = mk8(g5 ? sl[2] : ul[0], g5 ? sl[3] : ul[1],
            g5 ? ul[2] : sl[0], g5 ? ul[3] : sl[1]);
}

// W-plane read: 8B-granule, XOR-(row&15) — R11-proven layout.
__device__ __forceinline__ f16x8 ldfrag(const char* plane, int row, int kt, int g5) {
  int s = row & 15;
  int c8 = 4 * kt + 2 * g5;
  uint2 a = *(const uint2*)(plane + row * 128 + ((c8) ^ s) * 8);
  uint2 b = *(const uint2*)(plane + row * 128 + ((c8 + 1) ^ s) * 8);
  return mk8(a.x, a.y, b.x, b.y);
}

// ---------------- K1: [N,C,F,T] f32 -> x[B=n*256+t][F][C] f32 (into d_out) ----
__global__ __launch_bounds__(256) void k_pre32(const float* __restrict__ inp,
                                               float* __restrict__ xws) {
  __shared__ float tile[64 * 65];
  const int bid = blockIdx.x;
  const int n = bid >> 10;
  const int rem = bid & 1023;
  const int f = rem >> 2;
  const int t0 = (rem & 3) << 6;
  const int tid = threadIdx.x;

  const int tt = tid & 63, cb = tid >> 6;
  const float* src = inp + ((size_t)n * 64 * 256 + f) * 256 + t0;
#pragma unroll
  for (int k = 0; k < 16; ++k) {
    int c = cb * 16 + k;
    tile[c * 65 + tt] = src[(size_t)c * 65536 + tt];
  }
  __syncthreads();
  const int c2 = (tid & 31) * 2, tb = tid >> 5;
#pragma unroll
  for (int k = 0; k < 8; ++k) {
    int t = tb + 8 * k;
    float2 v = make_float2(tile[c2 * 65 + t], tile[(c2 + 1) * 65 + t]);
    *(float2*)(xws + ((size_t)(n * 256 + t0 + t) * 256 + f) * 64 + c2) = v;
  }
}

// ---------------- K2: fused LN1+QKV+attn+LN2+proj+LN3+PReLU ----------------
// 512 threads = 8 waves; wave w owns F-rows [32w, 32w+32).
// x stays f32 (R17 proved f16-x costs +0.14 absmax — over budget).
// K/V: 16B-chunk xor-7, aligned strides (R14). P single-f16 (R15).
// W planes: 8B-granule xor-15 (R11). s_setprio around MFMA clusters (T5).
__global__ __launch_bounds__(512, 2) void k_attn(
    const float* __restrict__ xg,  // x f32 [b][f][c] (staged in d_out)
    u16* __restrict__ yws,         // y f16 out
    const float* __restrict__ Wq, const float* __restrict__ bq,
    const float* __restrict__ Wk, const float* __restrict__ bk,
    const float* __restrict__ Wv, const float* __restrict__ bv,
    const float* __restrict__ g1, const float* __restrict__ b1,
    const float* __restrict__ g2, const float* __restrict__ b2,
    const float* __restrict__ Wt, const float* __restrict__ bt,
    const float* __restrict__ g3, const float* __restrict__ b3,
    const float* __restrict__ alp) {
  extern __shared__ char smem[];
  char* Khi = smem;                  // K hi f16 [256][128B], 16B-chunk xor-7
  char* Klo = smem + 32768;          // K residual*512
  char* Vlds = smem + 65536;         // Vt f16 [64][512B], 16B-chunk xor-7
  char* WkH = smem + 98304;          // W planes: [64 rows][16 granules], xor-15
  char* WkL = smem + 106496;
  char* WvH = smem + 114688;
  char* WvL = smem + 122880;
  char* WqH = smem + 131072;
  char* WqL = smem + 139264;
  char* WtH = smem + 147456;         // -> total 155648 B

  const int tid = threadIdx.x;
  const int w = tid >> 6;          // 0..7
  const int lane = tid & 63;
  const int l31 = lane & 31;
  const int g5 = lane >> 5;
  const int l7 = l31 & 7;
  const int b = blockIdx.x;
  const float* xb = xg + (size_t)b * 16384;
  const float RLO = 1.f / 512.f;

  // ---- issue x loads early (f32; latency hides under W-prep) ----
  float xv[32];
  {
    int f = 32 * w + l31;
#pragma unroll
    for (int kt = 0; kt < 4; ++kt) {
      float4 a = *(const float4*)(xb + f * 64 + 16 * kt + 8 * g5);
      float4 c = *(const float4*)(xb + f * 64 + 16 * kt + 8 * g5 + 4);
      xv[kt * 8 + 0] = a.x; xv[kt * 8 + 1] = a.y;
      xv[kt * 8 + 2] = a.z; xv[kt * 8 + 3] = a.w;
      xv[kt * 8 + 4] = c.x; xv[kt * 8 + 5] = c.y;
      xv[kt * 8 + 6] = c.z; xv[kt * 8 + 7] = c.w;
    }
  }

  // ---- Phase 0: cooperative W -> LDS split-pack (R11 8B-granule scheme) ----
  {
    const int prow = tid >> 3, pc = tid & 7;
    const int ps = prow & 15;
    const int pha = (2 * pc) ^ ps, phb = (2 * pc + 1) ^ ps;
    const size_t off = (size_t)prow * 64 + pc * 8;
    {
      float4 a = *(const float4*)(Wk + off);
      float4 c = *(const float4*)(Wk + off + 4);
      u32 h0, l0, h1, l1, h2, l2, h3, l3;
      sp2(a.x, a.y, 512.f, &h0, &l0); sp2(a.z, a.w, 512.f, &h1, &l1);
      sp2(c.x, c.y, 512.f, &h2, &l2); sp2(c.z, c.w, 512.f, &h3, &l3);
      *(uint2*)(WkH + prow * 128 + pha * 8) = make_uint2(h0, h1);
      *(uint2*)(WkH + prow * 128 + phb * 8) = make_uint2(h2, h3);
      *(uint2*)(WkL + prow * 128 + pha * 8) = make_uint2(l0, l1);
      *(uint2*)(WkL + prow * 128 + phb * 8) = make_uint2(l2, l3);
    }
    {
      float4 a = *(const float4*)(Wv + off);
      float4 c = *(const float4*)(Wv + off + 4);
      u32 h0, l0, h1, l1, h2, l2, h3, l3;
      sp2(a.x, a.y, 512.f, &h0, &l0); sp2(a.z, a.w, 512.f, &h1, &l1);
      sp2(c.x, c.y, 512.f, &h2, &l2); sp2(c.z, c.w, 512.f, &h3, &l3);
      *(uint2*)(WvH + prow * 128 + pha * 8) = make_uint2(h0, h1);
      *(uint2*)(WvH + prow * 128 + phb * 8) = make_uint2(h2, h3);
      *(uint2*)(WvL + prow * 128 + pha * 8) = make_uint2(l0, l1);
      *(uint2*)(WvL + prow * 128 + phb * 8) = make_uint2(l2, l3);
    }
    {
      float4 a = *(const float4*)(Wq + off);
      float4 c = *(const float4*)(Wq + off + 4);
      u32 h0, l0, h1, l1, h2, l2, h3, l3;
      sp2(a.x, a.y, 512.f, &h0, &l0); sp2(a.z, a.w, 512.f, &h1, &l1);
      sp2(c.x, c.y, 512.f, &h2, &l2); sp2(c.z, c.w, 512.f, &h3, &l3);
      *(uint2*)(WqH + prow * 128 + pha * 8) = make_uint2(h0, h1);
      *(uint2*)(WqH + prow * 128 + phb * 8) = make_uint2(h2, h3);
      *(uint2*)(WqL + prow * 128 + pha * 8) = make_uint2(l0, l1);
      *(uint2*)(WqL + prow * 128 + phb * 8) = make_uint2(l2, l3);
    }
    {
      float4 a = *(const float4*)(Wt + off);
      float4 c = *(const float4*)(Wt + off + 4);
      *(uint2*)(WtH + prow * 128 + pha * 8) = make_uint2(pk2(a.x, a.y), pk2(a.z, a.w));
      *(uint2*)(WtH + prow * 128 + phb * 8) = make_uint2(pk2(c.x, c.y), pk2(c.z, c.w));
    }
  }
  __syncthreads();

  // ---- LN1 (f32) -> split h fragments ----
  f16x8 hhi[4], hlo[4];
  {
    float s = 0.f, sq = 0.f;
#pragma unroll
    for (int i = 0; i < 32; ++i) { s += xv[i]; sq += xv[i] * xv[i]; }
    s += __shfl_xor(s, 32);
    sq += __shfl_xor(sq, 32);
    float mean = s * (1.f / 64.f);
    float var = sq * (1.f / 64.f) - mean * mean;
    float rs = rsqrtf(var + 1e-5f);
#pragma unroll
    for (int kt = 0; kt < 4; ++kt) {
      int c0 = 16 * kt + 8 * g5;
      u32 ph[4], pl[4];
#pragma unroll
      for (int j = 0; j < 4; ++j) {
        float v0 = (xv[kt * 8 + 2 * j] - mean) * rs * g1[c0 + 2 * j] + b1[c0 + 2 * j];
        float v1 = (xv[kt * 8 + 2 * j + 1] - mean) * rs * g1[c0 + 2 * j + 1] + b1[c0 + 2 * j + 1];
        sp2(v0, v1, 512.f, &ph[j], &pl[j]);
      }
      hhi[kt] = mk8(ph[0], ph[1], ph[2], ph[3]);
      hlo[kt] = mk8(pl[0], pl[1], pl[2], pl[3]);
    }
  }

  // ---- K = (Wk split)(h split) + bk -> split store Khi/Klo (16B chunks) ----
  {
    f32x16 ah[2] = {}, al[2] = {};
#pragma unroll
    for (int kt = 0; kt < 4; ++kt) {
#pragma unroll
      for (int ot = 0; ot < 2; ++ot) {
        f16x8 mh = ldfrag(WkH, l31 + 32 * ot, kt, g5);
        f16x8 ml = ldfrag(WkL, l31 + 32 * ot, kt, g5);
        __builtin_amdgcn_s_setprio(1);
        ah[ot] = MFMA(mh, hhi[kt], ah[ot]);
        al[ot] = MFMA(mh, hlo[kt], al[ot]);
        al[ot] = MFMA(ml, hhi[kt], al[ot]);
        __builtin_amdgcn_s_setprio(0);
      }
    }
    int fk = 32 * w + l31;
    int sw = l7;
#pragma unroll
    for (int ot = 0; ot < 2; ++ot) {
#pragma unroll
      for (int rq = 0; rq < 4; ++rq) {
        int o0 = 32 * ot + 8 * rq + 4 * g5;
        float4 bb = *(const float4*)(bk + o0);
        float k0 = ah[ot][4 * rq + 0] + al[ot][4 * rq + 0] * RLO + bb.x;
        float k1 = ah[ot][4 * rq + 1] + al[ot][4 * rq + 1] * RLO + bb.y;
        float k2 = ah[ot][4 * rq + 2] + al[ot][4 * rq + 2] * RLO + bb.z;
        float k3 = ah[ot][4 * rq + 3] + al[ot][4 * rq + 3] * RLO + bb.w;
        u32 h01, l01, h23, l23;
        sp2(k0, k1, 512.f, &h01, &l01);
        sp2(k2, k3, 512.f, &h23, &l23);
        int ch = (4 * ot + rq) ^ sw;
        *(uint2*)(Khi + fk * 128 + ch * 16 + 8 * g5) = make_uint2(h01, h23);
        *(uint2*)(Klo + fk * 128 + ch * 16 + 8 * g5) = make_uint2(l01, l23);
      }
    }
  }

  // ---- V = (Wv split)(h split) + bv -> Vt single f16 (16B chunks) ----
  {
    f32x16 ah[2] = {}, al[2] = {};
#pragma unroll
    for (int kt = 0; kt < 4; ++kt) {
#pragma unroll
      for (int nt = 0; nt < 2; ++nt) {
        f16x8 mh = ldfrag(WvH, l31 + 32 * nt, kt, g5);
        f16x8 ml = ldfrag(WvL, l31 + 32 * nt, kt, g5);
        __builtin_amdgcn_s_setprio(1);
        ah[nt] = MFMA(hhi[kt], mh, ah[nt]);
        al[nt] = MFMA(hlo[kt], mh, al[nt]);
        al[nt] = MFMA(hhi[kt], ml, al[nt]);
        __builtin_amdgcn_s_setprio(0);
      }
    }
#pragma unroll
    for (int nt = 0; nt < 2; ++nt) {
      int hh = l31 + 32 * nt;
      float bvj = bv[hh];
      int sw = hh & 7;
#pragma unroll
      for (int rq = 0; rq < 4; ++rq) {
        float v0 = ah[nt][4 * rq + 0] + al[nt][4 * rq + 0] * RLO + bvj;
        float v1 = ah[nt][4 * rq + 1] + al[nt][4 * rq + 1] * RLO + bvj;
        float v2 = ah[nt][4 * rq + 2] + al[nt][4 * rq + 2] * RLO + bvj;
        float v3 = ah[nt][4 * rq + 3] + al[nt][4 * rq + 3] * RLO + bvj;
        int ch = (4 * w + rq) ^ sw;
        *(uint2*)(Vlds + hh * 512 + ch * 16 + 8 * g5) =
            make_uint2(pk2(v0, v1), pk2(v2, v3));
      }
    }
  }

  // ---- Q' = ((Wq split)(h split) + bq)*qs, split B-fragments in regs ----
  f16x8 qf[4], ql[4];
  {
    f32x16 ah[2] = {}, al[2] = {};
#pragma unroll
    for (int kt = 0; kt < 4; ++kt) {
#pragma unroll
      for (int ot = 0; ot < 2; ++ot) {
        f16x8 mh = ldfrag(WqH, l31 + 32 * ot, kt, g5);
        f16x8 ml = ldfrag(WqL, l31 + 32 * ot, kt, g5);
        __builtin_amdgcn_s_setprio(1);
        ah[ot] = MFMA(mh, hhi[kt], ah[ot]);
        al[ot] = MFMA(mh, hlo[kt], al[ot]);
        al[ot] = MFMA(ml, hhi[kt], al[ot]);
        __builtin_amdgcn_s_setprio(0);
      }
    }
    const float qs = 0.18033688011112042f;  // log2(e)/sqrt(64)
#pragma unroll
    for (int ot = 0; ot < 2; ++ot) {
#pragma unroll
      for (int rq = 0; rq < 4; ++rq) {
        int o0 = 32 * ot + 8 * rq + 4 * g5;
        float4 bb = *(const float4*)(bq + o0);
        ah[ot][4 * rq + 0] = (ah[ot][4 * rq + 0] + al[ot][4 * rq + 0] * RLO + bb.x) * qs;
        ah[ot][4 * rq + 1] = (ah[ot][4 * rq + 1] + al[ot][4 * rq + 1] * RLO + bb.y) * qs;
        ah[ot][4 * rq + 2] = (ah[ot][4 * rq + 2] + al[ot][4 * rq + 2] * RLO + bb.z) * qs;
        ah[ot][4 * rq + 3] = (ah[ot][4 * rq + 3] + al[ot][4 * rq + 3] * RLO + bb.w) * qs;
      }
    }
#pragma unroll
    for (int kt = 0; kt < 4; ++kt)
      xfrag2(ah[kt >> 1], kt & 1, g5, &qf[kt], &ql[kt], 512.f);
  }

  __syncthreads();

  const float alv = alp[0];
  const float btc0 = bt[l31], btc1 = bt[l31 + 32];
  const float g3v0 = g3[l31], g3v1 = g3[l31 + 32];
  const float b3v0 = b3[l31], b3v1 = b3[l31 + 32];
  u16* yb = yws + (size_t)b * 16384;

  // ---- E^T = (Khi+Klo/S)·(Qhi+Qlo/S)^T : D[fk][fq], fq = 32w + l31 ----
  f32x16 e[8];
#pragma unroll
  for (int m = 0; m < 8; ++m) {
    const char* krh = Khi + (l31 + 32 * m) * 128;
    const char* krl = Klo + (l31 + 32 * m) * 128;
    f32x16 eh = {}, em = {};
#pragma unroll
    for (int kt = 0; kt < 4; ++kt) {
      int ch = (2 * kt + g5) ^ l7;
      f16x8 kh = __builtin_bit_cast(f16x8, *(const uint4*)(krh + ch * 16));
      f16x8 kl = __builtin_bit_cast(f16x8, *(const uint4*)(krl + ch * 16));
      __builtin_amdgcn_s_setprio(1);
      eh = MFMA(kh, qf[kt], eh);
      em = MFMA(kh, ql[kt], em);
      em = MFMA(kl, qf[kt], em);
      __builtin_amdgcn_s_setprio(0);
    }
#pragma unroll
    for (int r = 0; r < 16; ++r) e[m][r] = eh[r] + em[r] * RLO;
  }
  // ---- softmax over fk ----
  float mx = -3.0e38f;
#pragma unroll
  for (int m = 0; m < 8; ++m)
#pragma unroll
    for (int r = 0; r < 16; ++r) mx = fmaxf(mx, e[m][r]);
  mx = fmaxf(mx, __shfl_xor(mx, 32));
  float s = 0.f;
#pragma unroll
  for (int m = 0; m < 8; ++m)
#pragma unroll
    for (int r = 0; r < 16; ++r) {
      float p = ex2(e[m][r] - mx);
      e[m][r] = p;
      s += p;
    }
  s += __shfl_xor(s, 32);
  float rcps = 1.0f / s;

  // ---- WV^T = Vt · P^T (P single f16 — R15-proven) ----
  f32x16 wv0 = {}, wv1 = {};
#pragma unroll
  for (int kt = 0; kt < 16; ++kt) {
    f16x8 pf = xfrag(e[kt >> 1], kt & 1, g5);
    int ch = (2 * kt + g5) ^ l7;
    f16x8 vaf = __builtin_bit_cast(f16x8, *(const uint4*)(Vlds + l31 * 512 + ch * 16));
    f16x8 vbf = __builtin_bit_cast(f16x8, *(const uint4*)(Vlds + (l31 + 32) * 512 + ch * 16));
    __builtin_amdgcn_s_setprio(1);
    wv0 = MFMA(vaf, pf, wv0);
    wv1 = MFMA(vbf, pf, wv1);
    __builtin_amdgcn_s_setprio(0);
  }

  // ---- LN2 over h (apply softmax denom here) ----
  float s2 = 0.f, sq2 = 0.f;
#pragma unroll
  for (int r = 0; r < 16; ++r) {
    float a = wv0[r] * rcps; wv0[r] = a; s2 += a; sq2 += a * a;
    float c = wv1[r] * rcps; wv1[r] = c; s2 += c; sq2 += c * c;
  }
  s2 += __shfl_xor(s2, 32);
  sq2 += __shfl_xor(sq2, 32);
  float m2 = s2 * (1.f / 64.f);
  float v2 = sq2 * (1.f / 64.f) - m2 * m2;
  float rs2 = rsqrtf(v2 + 1e-5f);
#pragma unroll
  for (int at = 0; at < 2; ++at) {
#pragma unroll
    for (int rq = 0; rq < 4; ++rq) {
      int h0 = 32 * at + 8 * rq + 4 * g5;
      float4 gg = *(const float4*)(g2 + h0);
      float4 bb = *(const float4*)(b2 + h0);
      f32x16& a = at ? wv1 : wv0;
      a[4 * rq + 0] = (a[4 * rq + 0] - m2) * rs2 * gg.x + bb.x;
      a[4 * rq + 1] = (a[4 * rq + 1] - m2) * rs2 * gg.y + bb.y;
      a[4 * rq + 2] = (a[4 * rq + 2] - m2) * rs2 * gg.z + bb.z;
      a[4 * rq + 3] = (a[4 * rq + 3] - m2) * rs2 * gg.w + bb.w;
    }
  }
  f16x8 afh[4], afl[4];
  xfrag2(wv0, 0, g5, &afh[0], &afl[0], 1.f);
  xfrag2(wv0, 1, g5, &afh[1], &afl[1], 1.f);
  xfrag2(wv1, 0, g5, &afh[2], &afl[2], 1.f);
  xfrag2(wv1, 1, g5, &afh[3], &afl[3], 1.f);

  // ---- OUT = WVln · Wt^T : D[f][c] ----
  f32x16 o0 = {}, o1 = {};
#pragma unroll
  for (int kt = 0; kt < 4; ++kt) {
    f16x8 w0 = ldfrag(WtH, l31, kt, g5);
    f16x8 w1 = ldfrag(WtH, l31 + 32, kt, g5);
    __builtin_amdgcn_s_setprio(1);
    o0 = MFMA(afh[kt], w0, o0);
    o0 = MFMA(afl[kt], w0, o0);
    o1 = MFMA(afh[kt], w1, o1);
    o1 = MFMA(afl[kt], w1, o1);
    __builtin_amdgcn_s_setprio(0);
  }

  // ---- +bt, LN3 over c (red32 butterfly per row), PReLU, store y f16 ----
  const int fbase = 32 * w + 4 * g5;
#pragma unroll
  for (int r = 0; r < 16; ++r) {
    float v0 = o0[r] + btc0;
    float v1 = o1[r] + btc1;
    float S = red32(v0 + v1);
    float SQ = red32(v0 * v0 + v1 * v1);
    float m3 = S * (1.f / 64.f);
    float va = SQ * (1.f / 64.f) - m3 * m3;
    float rs3 = rsqrtf(va + 1e-5f);
    float y0 = (v0 - m3) * rs3 * g3v0 + b3v0;
    float y1 = (v1 - m3) * rs3 * g3v1 + b3v1;
    y0 = y0 >= 0.f ? y0 : alv * y0;
    y1 = y1 >= 0.f ? y1 : alv * y1;
    int f = fbase + (r & 3) + 8 * (r >> 2);
    u16* yp = yb + f * 64 + l31;
    yp[0] = f16b(y0);
    yp[32] = f16b(y1);
  }
}

// ---------------- K3: out[n,c,f,t] = inputs + y[b,f,c] (f32 out) ----------------
__global__ __launch_bounds__(256) void k_post(const float* __restrict__ inp,
                                              const u16* __restrict__ yws,
                                              float* __restrict__ out) {
  __shared__ float tile[64 * 66];
  const int bid = blockIdx.x;
  const int n = bid >> 10;
  const int rem = bid & 1023;
  const int f = rem >> 2;
  const int t0 = (rem & 3) << 6;
  const int tid = threadIdx.x;

  const int c2 = (tid & 31) * 2, tb = tid >> 5;
  const u32* src = (const u32*)yws;
#pragma unroll
  for (int k = 0; k < 8; ++k) {
    int t = tb + 8 * k;
    u32 v = src[((n * 256 + t0 + t) * 256 + f) * 32 + (tid & 31)];
    float2 p = up2(v);
    tile[t * 66 + c2] = p.x;
    tile[t * 66 + c2 + 1] = p.y;
  }
  __syncthreads();
  const int tt = tid & 63, cb = tid >> 6;
#pragma unroll
  for (int k = 0; k < 16; ++k) {
    int c = cb * 16 + k;
    size_t idx = ((size_t)(n * 64 + c) * 256 + f) * 256 + t0 + tt;
    out[idx] = inp[idx] + tile[tt * 66 + c];
  }
}

extern "C" void kernel_launch(void* const* d_in, const int* in_sizes, int n_in,
                              void* d_out, int out_size, void* d_ws, size_t ws_size,
                              hipStream_t stream) {
  const float* inp = (const float*)d_in[0];
  const float* Wq = (const float*)d_in[1];
  const float* bq = (const float*)d_in[2];
  const float* Wk = (const float*)d_in[3];
  const float* bk = (const float*)d_in[4];
  const float* Wv = (const float*)d_in[5];
  const float* bv = (const float*)d_in[6];
  const float* g1 = (const float*)d_in[7];
  const float* b1 = (const float*)d_in[8];
  const float* g2 = (const float*)d_in[9];
  const float* b2 = (const float*)d_in[10];
  const float* Wt = (const float*)d_in[11];
  const float* bt = (const float*)d_in[12];
  const float* g3 = (const float*)d_in[13];
  const float* b3 = (const float*)d_in[14];
  const float* al = (const float*)d_in[15];
  float* xstage = (float*)d_out;  // x f32 [b][f][c] = 128 MiB (k_post overwrites)
  u16* yws = (u16*)d_ws;          // y f16 [b][f][c] = 64 MiB

  (void)hipFuncSetAttribute((const void*)k_attn,
                            hipFuncAttributeMaxDynamicSharedMemorySize, 155648);
  k_pre32<<<8192, 256, 0, stream>>>(inp, xstage);
  k_attn<<<2048, 512, 155648, stream>>>(xstage, yws, Wq, bq, Wk, bk, Wv, bv,
                                        g1, b1, g2, b2, Wt, bt, g3, b3, al);
  k_post<<<8192, 256, 0, stream>>>(inp, yws, (float*)d_out);
}